// Round 15
// baseline (1227.507 us; speedup 1.0000x reference)
//
#include <hip/hip_runtime.h>
#include <cstdint>

// ---------------------------------------------------------------------------
// Round 15: revert GEMMs to r13 (BM=128, 243.1 µs; r14's BM=256 regressed
// 77µs/gemm via VALU addressing bloat). New: routing+assign+gather+transposes
// fused into ONE ticketed dispatch (ticket order: 64 routing -> 1 assign ->
// 4096 transposes (no dep, overlap routing) -> 9216 gathers (spin on
// assign_done)). Deadlock-free: spinners take tickets only after their
// producers did (producers resident-or-done). Agent-scope fences for
// cross-XCD visibility. 6 -> 4 dispatches.
// ---------------------------------------------------------------------------

#define T_TOK 4096
#define D_DIM 512
#define F_DIM 2048
#define E_EXP 8
#define NROWS 9216      // 8192 assignments + 8*128 pad
#define MAXTILES 72     // NROWS / 128

typedef __bf16 bf16x8 __attribute__((ext_vector_type(8)));
typedef float  f32x4  __attribute__((ext_vector_type(4)));
typedef unsigned short u16;

__device__ __forceinline__ u16 f2b(float f) {
    return __builtin_bit_cast(unsigned short, (__bf16)f);
}
__device__ __forceinline__ void gload16(void* lds, const void* g) {
    __builtin_amdgcn_global_load_lds(
        (const __attribute__((address_space(1))) void*)g,
        (__attribute__((address_space(3))) void*)lds, 16, 0, 0);
}
// tanh-approx GELU (err ~3e-4 << bf16 ulp)
__device__ __forceinline__ float gelu_f(float v) {
    float z = 0.7978845608f * (v + 0.044715f * v * v * v);
    float t = 1.0f - 2.0f / (1.0f + __expf(2.0f * z));
    return 0.5f * v * (1.0f + t);
}

// ---------------- init (zeroing + sync words) + anchors ---------------------
__global__ void init_k(int* __restrict__ cnt, int* __restrict__ rowmap,
                       float* __restrict__ rowgate, float* __restrict__ outm,
                       int* __restrict__ sync,
                       const float* __restrict__ anchors,
                       float* __restrict__ an, float* __restrict__ dout_an) {
    int tid = blockIdx.x * 256 + threadIdx.x;
    int nth = gridDim.x * 256;
    if (tid < E_EXP) cnt[tid] = 0;
    if (tid < 4) sync[tid] = 0;          // [0]=ticket [1]=routing_done [2]=assign_done
    for (int i = tid; i < NROWS; i += nth) { rowmap[i] = -1; rowgate[i] = 0.f; }
    float4* o4 = (float4*)outm;
    for (int i = tid; i < (T_TOK * D_DIM) / 4; i += nth)
        o4[i] = float4{0.f, 0.f, 0.f, 0.f};
    if (blockIdx.x == gridDim.x - 1) {   // anchor norms: 32 threads/anchor
        int t = threadIdx.x;
        int e = t >> 5, l = t & 31;
        const float4* ar = (const float4*)(anchors + e * D_DIM + l * 16);
        float4 v0 = ar[0], v1 = ar[1], v2 = ar[2], v3 = ar[3];
        float ss = v0.x*v0.x + v0.y*v0.y + v0.z*v0.z + v0.w*v0.w
                 + v1.x*v1.x + v1.y*v1.y + v1.z*v1.z + v1.w*v1.w
                 + v2.x*v2.x + v2.y*v2.y + v2.z*v2.z + v2.w*v2.w
                 + v3.x*v3.x + v3.y*v3.y + v3.z*v3.z + v3.w*v3.w;
#pragma unroll
        for (int off = 16; off >= 1; off >>= 1) ss += __shfl_xor(ss, off, 32);
        float inv = 1.0f / fmaxf(sqrtf(ss), 1e-8f);
#pragma unroll
        for (int i = 0; i < 16; ++i) {
            float o;
            if (i < 4)       o = (&v0.x)[i] * inv;
            else if (i < 8)  o = (&v1.x)[i - 4] * inv;
            else if (i < 12) o = (&v2.x)[i - 8] * inv;
            else             o = (&v3.x)[i - 12] * inv;
            an[e * D_DIM + l * 16 + i] = o;
            dout_an[e * D_DIM + l * 16 + i] = o;
        }
    }
}

// ---------------- fused routing + assign + transposes + gather --------------
// ticket phases: [0,64) routing | 64 assign | [65,65+4096) transpose |
//                [65+4096, 65+4096+NROWS) gather
#define TK_ASSIGN 64
#define TK_TRANS  65
#define TK_GATHER (65 + 4096)
#define FUSED_BLOCKS (65 + 4096 + NROWS)

__global__ void fused_prep_k(const float* __restrict__ x, const float* __restrict__ an,
                             float* __restrict__ dout_scores, float* __restrict__ dout_idx,
                             int* __restrict__ idxs, float* __restrict__ gates,
                             int* __restrict__ cnt, int* __restrict__ offs,
                             int* __restrict__ rowmap, float* __restrict__ rowgate,
                             u16* __restrict__ Xg,
                             const float* __restrict__ W1, u16* __restrict__ W1T,
                             const float* __restrict__ W2, u16* __restrict__ W2T,
                             int* __restrict__ sync) {
    __shared__ char smem[17440];          // overlay: routing anl / transpose tile
    __shared__ int hist[E_EXP];
    __shared__ int s_t;
    int tid = threadIdx.x;
    if (tid == 0) s_t = atomicAdd(&sync[0], 1);
    __syncthreads();
    int t = s_t;

    if (t < TK_ASSIGN) {
        // ---------- routing (4 threads/token, 64 tokens/block) ----------
        float* anl = (float*)smem;        // [e][p*136 + i]
        if (tid < E_EXP) hist[tid] = 0;
        for (int i = tid; i < E_EXP * D_DIM; i += 256) {
            int e = i >> 9, d = i & 511;
            anl[e * 544 + (d >> 7) * 136 + (d & 127)] = an[i];
        }
        __syncthreads();
        int p = tid & 3;
        int tok = t * 64 + (tid >> 2);
        const float4* xr = (const float4*)(x + (size_t)tok * D_DIM + p * 128);
        const float* ab = &anl[p * 136];
        float dot[E_EXP] = {};
        float ss = 0.f;
        for (int c = 0; c < 32; ++c) {
            float4 xv = xr[c];
            ss += xv.x*xv.x + xv.y*xv.y + xv.z*xv.z + xv.w*xv.w;
#pragma unroll
            for (int e = 0; e < E_EXP; ++e) {
                float4 av = *(const float4*)&ab[e * 544 + c * 4];
                dot[e] += xv.x*av.x + xv.y*av.y + xv.z*av.z + xv.w*av.w;
            }
        }
#pragma unroll
        for (int off = 1; off <= 2; off <<= 1) {
            ss += __shfl_xor(ss, off, 64);
#pragma unroll
            for (int e = 0; e < E_EXP; ++e) dot[e] += __shfl_xor(dot[e], off, 64);
        }
        if (p == 0) {
            float inv = 1.0f / fmaxf(sqrtf(ss), 1e-8f);
            float s[E_EXP];
#pragma unroll
            for (int e = 0; e < E_EXP; ++e) s[e] = dot[e] * inv;
            int i0 = 0; float b0 = s[0];
#pragma unroll
            for (int e = 1; e < E_EXP; ++e) if (s[e] > b0) { b0 = s[e]; i0 = e; }
            int i1 = -1; float b1v = -1e30f;
#pragma unroll
            for (int e = 0; e < E_EXP; ++e)
                if (e != i0 && s[e] > b1v) { b1v = s[e]; i1 = e; }
            if (i1 < 0) { i1 = (i0 + 1) & 7; b1v = s[i1]; }   // NaN-safety
            float g0 = 1.0f / (1.0f + expf(b1v - b0));
            float g1 = 1.0f - g0;
#pragma unroll
            for (int e = 0; e < E_EXP; ++e) dout_scores[tok * E_EXP + e] = s[e];
            dout_idx[tok * 2 + 0] = (float)i0;
            dout_idx[tok * 2 + 1] = (float)i1;
            idxs[tok * 2 + 0] = i0; idxs[tok * 2 + 1] = i1;
            gates[tok * 2 + 0] = g0; gates[tok * 2 + 1] = g1;
            atomicAdd(&hist[i0], 1);
            atomicAdd(&hist[i1], 1);
        }
        __syncthreads();
        if (tid < E_EXP) atomicAdd(&cnt[tid], hist[tid]);
        __syncthreads();
        __threadfence();                  // publish idxs/gates/cnt (agent scope)
        if (tid == 0) atomicAdd(&sync[1], 1);
    } else if (t == TK_ASSIGN) {
        // ---------- offsets + slot assignment (spins on routing_done) ----
        if (tid == 0) {
            while (__hip_atomic_load(&sync[1], __ATOMIC_ACQUIRE,
                                     __HIP_MEMORY_SCOPE_AGENT) < 64)
                __builtin_amdgcn_s_sleep(8);
        }
        __syncthreads();
        __shared__ int scur[E_EXP];
        if (tid == 0) {
            int acc = 0;
            for (int e = 0; e < E_EXP; ++e) {
                offs[e] = acc; scur[e] = acc;
                acc += (cnt[e] + 127) & ~127;
            }
            offs[E_EXP] = acc;
        }
        __syncthreads();
        for (int tk = tid; tk < T_TOK; tk += 256) {
#pragma unroll
            for (int k = 0; k < 2; ++k) {
                int e = idxs[tk * 2 + k];
                e = min(max(e, 0), E_EXP - 1);
                int r = atomicAdd(&scur[e], 1);
                if (r >= 0 && r < NROWS) {
                    rowmap[r] = tk;
                    rowgate[r] = gates[tk * 2 + k];
                }
            }
        }
        __syncthreads();
        __threadfence();                  // publish rowmap/rowgate/offs
        if (tid == 0)
            __hip_atomic_store(&sync[2], 1, __ATOMIC_RELEASE,
                               __HIP_MEMORY_SCOPE_AGENT);
    } else if (t < TK_GATHER) {
        // ---------- weight transposes (no routing dependency) ------------
        float (*tsh)[65] = (float(*)[65])smem;
        int tt = t - TK_TRANS;
        const float* in; u16* outp; int R, C, c0, r0;
        if (tt < 2048) {                  // W1 [E][512][2048] -> [E][2048][512]
            int bx = tt & 31, by = (tt >> 5) & 7, bz = tt >> 8;
            size_t zoff = (size_t)bz * D_DIM * F_DIM;
            in = W1 + zoff; outp = W1T + zoff;
            R = D_DIM; C = F_DIM; c0 = bx * 64; r0 = by * 64;
        } else {                          // W2 [E][2048][512] -> [E][512][2048]
            tt -= 2048;
            int bx = tt & 7, by = (tt >> 3) & 31, bz = tt >> 8;
            size_t zoff = (size_t)bz * D_DIM * F_DIM;
            in = W2 + zoff; outp = W2T + zoff;
            R = F_DIM; C = D_DIM; c0 = bx * 64; r0 = by * 64;
        }
        int cq = tid & 15, rb = tid >> 4;
#pragma unroll
        for (int pass = 0; pass < 4; ++pass) {
            int rr = rb + pass * 16;
            float4 v = *(const float4*)(in + (size_t)(r0 + rr) * C + c0 + cq * 4);
            tsh[rr][cq * 4 + 0] = v.x; tsh[rr][cq * 4 + 1] = v.y;
            tsh[rr][cq * 4 + 2] = v.z; tsh[rr][cq * 4 + 3] = v.w;
        }
        __syncthreads();
        int rg = tid & 15, cb = tid >> 4;
#pragma unroll
        for (int pass = 0; pass < 4; ++pass) {
            int c = cb + pass * 16;
            ushort4 o;
            o.x = f2b(tsh[rg * 4 + 0][c]); o.y = f2b(tsh[rg * 4 + 1][c]);
            o.z = f2b(tsh[rg * 4 + 2][c]); o.w = f2b(tsh[rg * 4 + 3][c]);
            *(ushort4*)(outp + (size_t)(c0 + c) * R + r0 + rg * 4) = o;
        }
    } else {
        // ---------- gather (spins on assign_done) -------------------------
        if (tid == 0) {
            while (__hip_atomic_load(&sync[2], __ATOMIC_ACQUIRE,
                                     __HIP_MEMORY_SCOPE_AGENT) == 0)
                __builtin_amdgcn_s_sleep(8);
        }
        __syncthreads();
        int r = t - TK_GATHER;
        int tok = rowmap[r];
        int c = tid * 2;
        ushort2 o;
        if (tok < 0 || tok >= T_TOK) { o.x = 0; o.y = 0; }
        else {
            float2 v = *(const float2*)(x + (size_t)tok * D_DIM + c);
            o.x = f2b(v.x); o.y = f2b(v.y);
        }
        *(ushort2*)(Xg + (size_t)r * D_DIM + c) = o;
    }
}

// ---------------- grouped GEMM core (identical to round 13) -----------------
// MODE 0: Hg = bf16(gelu(Xg @ W1e^T + b1e))         (N=F, K=D), NT=16
// MODE 1: out[tok] += gate*(Hg @ W2e^T + [z0]b2e)   (N=D, K=F, split-K=2), NT=4
// 1D grid; tile = (L%8)*(total/8) + L/8  -> contiguous m-tile range per XCD.
template <int MODE>
__launch_bounds__(256, 4)
__global__ void gemm_k(const u16* __restrict__ A, int lda,
                       const u16* __restrict__ BtBase, int ldb,
                       u16* __restrict__ Hout, const float* __restrict__ b1,
                       float* __restrict__ outm, const float* __restrict__ b2,
                       const int* __restrict__ rowmap, const float* __restrict__ rowgate,
                       const int* __restrict__ offs, int kPer, int nT) {
    int L = blockIdx.x;
    int per = gridDim.x >> 3;
    int tile = (L & 7) * per + (L >> 3);
    int z = 0;
    if (MODE == 1) {                 // split-K 2: high half of tiles is z=1
        int half = gridDim.x >> 1;
        z = tile >= half; tile -= z * half;
    }
    int mtile = tile / nT;
    int n0 = (tile - mtile * nT) * 128;
    int row0 = mtile * 128;
    if (row0 >= offs[E_EXP]) return;
    int e = 0;
#pragma unroll
    for (int i = 1; i < E_EXP; ++i) if (row0 >= offs[i]) e = i;
    const u16* Bt = BtBase + (size_t)e * D_DIM * F_DIM;
    int k_begin = z * kPer;
    int k_end = k_begin + kPer;

    alignas(16) __shared__ u16 As[128 * 64];
    alignas(16) __shared__ u16 Bs[128 * 64];

    int tid = threadIdx.x;
    int lane = tid & 63;
    int wv = tid >> 6;
    int wm = wv & 1, wn = wv >> 1;
    int kq = lane >> 4;          // quad 0..3
    int l15 = lane & 15;

    // staging: slot = i*256 + tid; m = slot>>3; kc = slot&7 (linear)
    const u16* aSrc[4]; const u16* bSrc[4];
    u16* aDst[4]; u16* bDst[4];
#pragma unroll
    for (int i = 0; i < 4; ++i) {
        int slot = i * 256 + tid;
        int m = slot >> 3;
        int kc = slot & 7;
        aSrc[i] = A + (size_t)(row0 + m) * lda + kc * 8;
        bSrc[i] = Bt + (size_t)(n0 + m) * ldb + kc * 8;
        aDst[i] = As + slot * 8;
        bDst[i] = Bs + slot * 8;
    }

    f32x4 acc[4][4];
#pragma unroll
    for (int i = 0; i < 4; ++i)
#pragma unroll
        for (int j = 0; j < 4; ++j) acc[i][j] = f32x4{0.f, 0.f, 0.f, 0.f};

    for (int k0 = k_begin; k0 < k_end; k0 += 64) {
#pragma unroll
        for (int i = 0; i < 4; ++i) gload16(aDst[i], aSrc[i] + k0);
#pragma unroll
        for (int i = 0; i < 4; ++i) gload16(bDst[i], bSrc[i] + k0);
        asm volatile("s_waitcnt vmcnt(0)" ::: "memory");
        __syncthreads();
#pragma unroll
        for (int kk = 0; kk < 2; ++kk) {
            int kc = kk * 4 + kq;
            bf16x8 af[4], bfr[4];
#pragma unroll
            for (int i = 0; i < 4; ++i) {
                int rowA = wm * 64 + i * 16 + l15;
                af[i] = *(const bf16x8*)(As + rowA * 64 + kc * 8);
                int rowB = wn * 64 + i * 16 + l15;
                bfr[i] = *(const bf16x8*)(Bs + rowB * 64 + kc * 8);
            }
#pragma unroll
            for (int i = 0; i < 4; ++i)
#pragma unroll
                for (int j = 0; j < 4; ++j)
                    acc[i][j] = __builtin_amdgcn_mfma_f32_16x16x32_bf16(
                        af[i], bfr[j], acc[i][j], 0, 0, 0);
        }
        __syncthreads();
    }

    if constexpr (MODE == 0) {
        const float* b1e = b1 + (size_t)e * F_DIM;
#pragma unroll
        for (int i = 0; i < 4; ++i) {
            int gr = row0 + wm * 64 + i * 16 + kq * 4;
#pragma unroll
            for (int j = 0; j < 4; ++j) {
                int gc = n0 + wn * 64 + j * 16 + l15;
                float bb = b1e[gc];
#pragma unroll
                for (int r = 0; r < 4; ++r) {
                    float v = acc[i][j][r] + bb;
                    Hout[(size_t)(gr + r) * F_DIM + gc] = f2b(gelu_f(v));
                }
            }
        }
    } else {
        const float* b2e = b2 + (size_t)e * D_DIM;
        bool addBias = (k_begin == 0);
#pragma unroll
        for (int i = 0; i < 4; ++i) {
            int grb = row0 + wm * 64 + i * 16 + kq * 4;
#pragma unroll
            for (int r = 0; r < 4; ++r) {
                int tok = rowmap[grb + r];
                float g = rowgate[grb + r];
                if (tok >= 0 && tok < T_TOK) {
                    float* orow = outm + (size_t)tok * D_DIM;
#pragma unroll
                    for (int j = 0; j < 4; ++j) {
                        int gc = n0 + wn * 64 + j * 16 + l15;
                        float bb = addBias ? b2e[gc] : 0.f;
                        atomicAdd(orow + gc, g * (acc[i][j][r] + bb));
                    }
                }
            }
        }
    }
}

// ---------------- workspace layout (bytes) — total need ~81 MB --------------
#define OFF_AN      0u           // 16 KB fp32 a_n
#define OFF_CNT     0x10000u
#define OFF_OFFS    0x10100u
#define OFF_SYNC    0x10200u     // int[4]: ticket, routing_done, assign_done
#define OFF_IDX     0x20000u     // int[T*2]
#define OFF_GATE    0x28000u     // float[T*2]
#define OFF_ROWMAP  0x30000u     // int[NROWS]
#define OFF_ROWGATE 0x40000u     // float[NROWS]
#define OFF_XG      0x900000u    // 9.44 MB u16[NROWS*D]  -> ends 0x1200000
#define OFF_W1T     0x1200000u   // 16.78 MB u16[E][F][D] -> ends 0x2200000
#define OFF_W2T     0x2200000u   // 16.78 MB u16[E][D][F] -> ends 0x3200000
#define OFF_HG      0x3200000u   // 37.75 MB u16[NROWS*F] -> ends 0x5600000

extern "C" void kernel_launch(void* const* d_in, const int* in_sizes, int n_in,
                              void* d_out, int out_size, void* d_ws, size_t ws_size,
                              hipStream_t stream) {
    const float* x       = (const float*)d_in[0];
    const float* anchors = (const float*)d_in[1];
    const float* W1      = (const float*)d_in[2];
    const float* b1      = (const float*)d_in[3];
    const float* W2      = (const float*)d_in[4];
    const float* b2      = (const float*)d_in[5];
    float* out = (float*)d_out;

    char* ws = (char*)d_ws;
    float* an      = (float*)(ws + OFF_AN);
    int*   cnt     = (int*)(ws + OFF_CNT);
    int*   offs    = (int*)(ws + OFF_OFFS);
    int*   syncw   = (int*)(ws + OFF_SYNC);
    int*   idxs    = (int*)(ws + OFF_IDX);
    float* gates   = (float*)(ws + OFF_GATE);
    int*   rowmap  = (int*)(ws + OFF_ROWMAP);
    float* rowgate = (float*)(ws + OFF_ROWGATE);
    u16*   Xg      = (u16*)(ws + OFF_XG);
    u16*   W1T     = (u16*)(ws + OFF_W1T);
    u16*   W2T     = (u16*)(ws + OFF_W2T);
    u16*   Hg      = (u16*)(ws + OFF_HG);

    // d_out sections (fp32 elements): out | a_n | scores | topk_idx
    float* out_main   = out;
    float* out_an     = out + (size_t)T_TOK * D_DIM;
    float* out_scores = out_an + E_EXP * D_DIM;
    float* out_idx    = out_scores + (size_t)T_TOK * E_EXP;

    init_k<<<512, 256, 0, stream>>>(cnt, rowmap, rowgate, out_main, syncw,
                                    anchors, an, out_an);
    fused_prep_k<<<FUSED_BLOCKS, 256, 0, stream>>>(
        x, an, out_scores, out_idx, idxs, gates, cnt, offs,
        rowmap, rowgate, Xg, W1, W1T, W2, W2T, syncw);
    // gemm1: 16 n-tiles x 72 m-tiles = 1152 blocks (1D, XCD-swizzled)
    gemm_k<0><<<16 * MAXTILES, 256, 0, stream>>>(
        Xg, D_DIM, W1T, D_DIM, Hg, b1, nullptr, nullptr,
        rowmap, nullptr, offs, D_DIM, 16);
    // gemm2: 4 n-tiles x 72 m-tiles x splitK2 = 576 blocks (1D, XCD-swizzled)
    gemm_k<1><<<4 * MAXTILES * 2, 256, 0, stream>>>(
        Hg, F_DIM, W2T, F_DIM, nullptr, nullptr, out_main, b2,
        rowmap, rowgate, offs, F_DIM / 2, 4);
}

// Round 16
// 249.126 us; speedup vs baseline: 4.9273x; 4.9273x over previous
//
#include <hip/hip_runtime.h>
#include <cstdint>

// ---------------------------------------------------------------------------
// Round 16: r15's ticket scheme cost ~1.1ms (13k blocks serialized on ONE
// atomic address ~80ns each). Revert to r13 GEMMs/structure; re-do the fusion
// contention-free: route_trans_k = 64 routing blocks + 4096 transpose blocks
// (blockIdx-phased, overlap); assign via last-finisher idiom (64-participant
// acq_rel counter, no spinning). 5 dispatches: init, route_trans, gather,
// gemm1, gemm2.
// ---------------------------------------------------------------------------

#define T_TOK 4096
#define D_DIM 512
#define F_DIM 2048
#define E_EXP 8
#define NROWS 9216      // 8192 assignments + 8*128 pad
#define MAXTILES 72     // NROWS / 128

typedef __bf16 bf16x8 __attribute__((ext_vector_type(8)));
typedef float  f32x4  __attribute__((ext_vector_type(4)));
typedef unsigned short u16;

__device__ __forceinline__ u16 f2b(float f) {
    return __builtin_bit_cast(unsigned short, (__bf16)f);
}
__device__ __forceinline__ void gload16(void* lds, const void* g) {
    __builtin_amdgcn_global_load_lds(
        (const __attribute__((address_space(1))) void*)g,
        (__attribute__((address_space(3))) void*)lds, 16, 0, 0);
}
// tanh-approx GELU (err ~3e-4 << bf16 ulp)
__device__ __forceinline__ float gelu_f(float v) {
    float z = 0.7978845608f * (v + 0.044715f * v * v * v);
    float t = 1.0f - 2.0f / (1.0f + __expf(2.0f * z));
    return 0.5f * v * (1.0f + t);
}

// ---------------- init (zeroing + sync word) + anchors ----------------------
__global__ void init_k(int* __restrict__ cnt, int* __restrict__ rowmap,
                       float* __restrict__ rowgate, float* __restrict__ outm,
                       int* __restrict__ sync,
                       const float* __restrict__ anchors,
                       float* __restrict__ an, float* __restrict__ dout_an) {
    int tid = blockIdx.x * 256 + threadIdx.x;
    int nth = gridDim.x * 256;
    if (tid < E_EXP) cnt[tid] = 0;
    if (tid < 4) sync[tid] = 0;          // [0] = routing_done counter
    for (int i = tid; i < NROWS; i += nth) { rowmap[i] = -1; rowgate[i] = 0.f; }
    float4* o4 = (float4*)outm;
    for (int i = tid; i < (T_TOK * D_DIM) / 4; i += nth)
        o4[i] = float4{0.f, 0.f, 0.f, 0.f};
    if (blockIdx.x == gridDim.x - 1) {   // anchor norms: 32 threads/anchor
        int t = threadIdx.x;
        int e = t >> 5, l = t & 31;
        const float4* ar = (const float4*)(anchors + e * D_DIM + l * 16);
        float4 v0 = ar[0], v1 = ar[1], v2 = ar[2], v3 = ar[3];
        float ss = v0.x*v0.x + v0.y*v0.y + v0.z*v0.z + v0.w*v0.w
                 + v1.x*v1.x + v1.y*v1.y + v1.z*v1.z + v1.w*v1.w
                 + v2.x*v2.x + v2.y*v2.y + v2.z*v2.z + v2.w*v2.w
                 + v3.x*v3.x + v3.y*v3.y + v3.z*v3.z + v3.w*v3.w;
#pragma unroll
        for (int off = 16; off >= 1; off >>= 1) ss += __shfl_xor(ss, off, 32);
        float inv = 1.0f / fmaxf(sqrtf(ss), 1e-8f);
        float o[16] = {v0.x*inv, v0.y*inv, v0.z*inv, v0.w*inv,
                       v1.x*inv, v1.y*inv, v1.z*inv, v1.w*inv,
                       v2.x*inv, v2.y*inv, v2.z*inv, v2.w*inv,
                       v3.x*inv, v3.y*inv, v3.z*inv, v3.w*inv};
#pragma unroll
        for (int i = 0; i < 16; ++i) {
            an[e * D_DIM + l * 16 + i] = o[i];
            dout_an[e * D_DIM + l * 16 + i] = o[i];
        }
    }
}

// ---------------- routing (64 blk) + transposes (4096 blk), one dispatch ----
// blocks [0,64): routing; last routing finisher performs assign (no spin).
// blocks [64, 64+4096): W1/W2 transpose tiles (independent -> overlap).
__global__ void route_trans_k(const float* __restrict__ x, const float* __restrict__ an,
                              float* __restrict__ dout_scores, float* __restrict__ dout_idx,
                              int* __restrict__ idxs, float* __restrict__ gates,
                              int* __restrict__ cnt, int* __restrict__ offs,
                              int* __restrict__ rowmap, float* __restrict__ rowgate,
                              const float* __restrict__ W1, u16* __restrict__ W1T,
                              const float* __restrict__ W2, u16* __restrict__ W2T,
                              int* __restrict__ sync) {
    __shared__ char smem[17440];      // overlay: routing anl / transpose tile
    int b = blockIdx.x;
    int tid = threadIdx.x;

    if (b >= 64) {
        // ---------------- weight transpose tile -------------------------
        float (*tsh)[65] = (float(*)[65])smem;
        int tt = b - 64;
        const float* in; u16* outp; int R, C, c0, r0;
        if (tt < 2048) {              // W1 [E][512][2048] -> [E][2048][512]
            int bx = tt & 31, by = (tt >> 5) & 7, bz = tt >> 8;
            size_t zoff = (size_t)bz * D_DIM * F_DIM;
            in = W1 + zoff; outp = W1T + zoff;
            R = D_DIM; C = F_DIM; c0 = bx * 64; r0 = by * 64;
        } else {                      // W2 [E][2048][512] -> [E][512][2048]
            tt -= 2048;
            int bx = tt & 7, by = (tt >> 3) & 31, bz = tt >> 8;
            size_t zoff = (size_t)bz * D_DIM * F_DIM;
            in = W2 + zoff; outp = W2T + zoff;
            R = F_DIM; C = D_DIM; c0 = bx * 64; r0 = by * 64;
        }
        int cq = tid & 15, rb = tid >> 4;
#pragma unroll
        for (int pass = 0; pass < 4; ++pass) {
            int rr = rb + pass * 16;
            float4 v = *(const float4*)(in + (size_t)(r0 + rr) * C + c0 + cq * 4);
            tsh[rr][cq * 4 + 0] = v.x; tsh[rr][cq * 4 + 1] = v.y;
            tsh[rr][cq * 4 + 2] = v.z; tsh[rr][cq * 4 + 3] = v.w;
        }
        __syncthreads();
        int rg = tid & 15, cb = tid >> 4;
#pragma unroll
        for (int pass = 0; pass < 4; ++pass) {
            int c = cb + pass * 16;
            ushort4 o;
            o.x = f2b(tsh[rg * 4 + 0][c]); o.y = f2b(tsh[rg * 4 + 1][c]);
            o.z = f2b(tsh[rg * 4 + 2][c]); o.w = f2b(tsh[rg * 4 + 3][c]);
            *(ushort4*)(outp + (size_t)(c0 + c) * R + r0 + rg * 4) = o;
        }
        return;
    }

    // ---------------- routing (4 threads/token, 64 tokens/block) ---------
    __shared__ int hist[E_EXP];
    __shared__ int amLast;
    float* anl = (float*)smem;        // [e][p*136 + i]
    if (tid < E_EXP) hist[tid] = 0;
    for (int i = tid; i < E_EXP * D_DIM; i += 256) {
        int e = i >> 9, d = i & 511;
        anl[e * 544 + (d >> 7) * 136 + (d & 127)] = an[i];
    }
    __syncthreads();
    int p = tid & 3;
    int tok = b * 64 + (tid >> 2);
    const float4* xr = (const float4*)(x + (size_t)tok * D_DIM + p * 128);
    const float* ab = &anl[p * 136];
    float dot[E_EXP] = {};
    float ss = 0.f;
    for (int c = 0; c < 32; ++c) {
        float4 xv = xr[c];
        ss += xv.x*xv.x + xv.y*xv.y + xv.z*xv.z + xv.w*xv.w;
#pragma unroll
        for (int e = 0; e < E_EXP; ++e) {
            float4 av = *(const float4*)&ab[e * 544 + c * 4];
            dot[e] += xv.x*av.x + xv.y*av.y + xv.z*av.z + xv.w*av.w;
        }
    }
#pragma unroll
    for (int off = 1; off <= 2; off <<= 1) {
        ss += __shfl_xor(ss, off, 64);
#pragma unroll
        for (int e = 0; e < E_EXP; ++e) dot[e] += __shfl_xor(dot[e], off, 64);
    }
    if (p == 0) {
        float inv = 1.0f / fmaxf(sqrtf(ss), 1e-8f);
        float s[E_EXP];
#pragma unroll
        for (int e = 0; e < E_EXP; ++e) s[e] = dot[e] * inv;
        int i0 = 0; float b0 = s[0];
#pragma unroll
        for (int e = 1; e < E_EXP; ++e) if (s[e] > b0) { b0 = s[e]; i0 = e; }
        int i1 = -1; float b1v = -1e30f;
#pragma unroll
        for (int e = 0; e < E_EXP; ++e)
            if (e != i0 && s[e] > b1v) { b1v = s[e]; i1 = e; }
        if (i1 < 0) { i1 = (i0 + 1) & 7; b1v = s[i1]; }   // NaN-safety
        float g0 = 1.0f / (1.0f + expf(b1v - b0));
        float g1 = 1.0f - g0;
#pragma unroll
        for (int e = 0; e < E_EXP; ++e) dout_scores[tok * E_EXP + e] = s[e];
        dout_idx[tok * 2 + 0] = (float)i0;
        dout_idx[tok * 2 + 1] = (float)i1;
        idxs[tok * 2 + 0] = i0; idxs[tok * 2 + 1] = i1;
        gates[tok * 2 + 0] = g0; gates[tok * 2 + 1] = g1;
        atomicAdd(&hist[i0], 1);
        atomicAdd(&hist[i1], 1);
    }
    __syncthreads();
    if (tid < E_EXP) atomicAdd(&cnt[tid], hist[tid]);
    __syncthreads();
    // last-finisher performs assign (64 participants on one counter: cheap)
    if (tid == 0) {
        __threadfence();              // publish idxs/gates/cnt device-wide
        int old = __hip_atomic_fetch_add(&sync[0], 1, __ATOMIC_ACQ_REL,
                                         __HIP_MEMORY_SCOPE_AGENT);
        amLast = (old == 63);
    }
    __syncthreads();
    if (!amLast) return;

    // ---------------- assign (this block only, all 256 threads) ----------
    __shared__ int scur[E_EXP];
    if (tid == 0) {
        int acc = 0;
        for (int e = 0; e < E_EXP; ++e) {
            int c = __hip_atomic_load(&cnt[e], __ATOMIC_ACQUIRE,
                                      __HIP_MEMORY_SCOPE_AGENT);
            offs[e] = acc; scur[e] = acc;
            acc += (c + 127) & ~127;
        }
        offs[E_EXP] = acc;
    }
    __syncthreads();
    for (int tk = tid; tk < T_TOK; tk += 256) {
#pragma unroll
        for (int k = 0; k < 2; ++k) {
            int e = idxs[tk * 2 + k];
            e = min(max(e, 0), E_EXP - 1);
            int r = atomicAdd(&scur[e], 1);
            if (r >= 0 && r < NROWS) {
                rowmap[r] = tk;
                rowgate[r] = gates[tk * 2 + k];
            }
        }
    }
}

// ---------------- gather tokens -> bf16 rows (pad rows zeroed) --------------
__global__ void gather_k(const float* __restrict__ x, const int* __restrict__ rowmap,
                         u16* __restrict__ Xg) {
    int r = blockIdx.x;
    int t = rowmap[r];
    int c = threadIdx.x * 2;     // 256 threads x 2 = 512 elems
    ushort2 o;
    if (t < 0 || t >= T_TOK) { o.x = 0; o.y = 0; }
    else {
        float2 v = *(const float2*)(x + (size_t)t * D_DIM + c);
        o.x = f2b(v.x); o.y = f2b(v.y);
    }
    *(ushort2*)(Xg + (size_t)r * D_DIM + c) = o;
}

// ---------------- grouped GEMM core (identical to round 13) -----------------
// MODE 0: Hg = bf16(gelu(Xg @ W1e^T + b1e))         (N=F, K=D), NT=16
// MODE 1: out[tok] += gate*(Hg @ W2e^T + [z0]b2e)   (N=D, K=F, split-K=2), NT=4
// 1D grid; tile = (L%8)*(total/8) + L/8  -> contiguous m-tile range per XCD.
template <int MODE>
__launch_bounds__(256, 4)
__global__ void gemm_k(const u16* __restrict__ A, int lda,
                       const u16* __restrict__ BtBase, int ldb,
                       u16* __restrict__ Hout, const float* __restrict__ b1,
                       float* __restrict__ outm, const float* __restrict__ b2,
                       const int* __restrict__ rowmap, const float* __restrict__ rowgate,
                       const int* __restrict__ offs, int kPer, int nT) {
    int L = blockIdx.x;
    int per = gridDim.x >> 3;
    int tile = (L & 7) * per + (L >> 3);
    int z = 0;
    if (MODE == 1) {                 // split-K 2: high half of tiles is z=1
        int half = gridDim.x >> 1;
        z = tile >= half; tile -= z * half;
    }
    int mtile = tile / nT;
    int n0 = (tile - mtile * nT) * 128;
    int row0 = mtile * 128;
    if (row0 >= offs[E_EXP]) return;
    int e = 0;
#pragma unroll
    for (int i = 1; i < E_EXP; ++i) if (row0 >= offs[i]) e = i;
    const u16* Bt = BtBase + (size_t)e * D_DIM * F_DIM;
    int k_begin = z * kPer;
    int k_end = k_begin + kPer;

    alignas(16) __shared__ u16 As[128 * 64];
    alignas(16) __shared__ u16 Bs[128 * 64];

    int tid = threadIdx.x;
    int lane = tid & 63;
    int wv = tid >> 6;
    int wm = wv & 1, wn = wv >> 1;
    int kq = lane >> 4;          // quad 0..3
    int l15 = lane & 15;

    // staging: slot = i*256 + tid; m = slot>>3; kc = slot&7 (linear)
    const u16* aSrc[4]; const u16* bSrc[4];
    u16* aDst[4]; u16* bDst[4];
#pragma unroll
    for (int i = 0; i < 4; ++i) {
        int slot = i * 256 + tid;
        int m = slot >> 3;
        int kc = slot & 7;
        aSrc[i] = A + (size_t)(row0 + m) * lda + kc * 8;
        bSrc[i] = Bt + (size_t)(n0 + m) * ldb + kc * 8;
        aDst[i] = As + slot * 8;
        bDst[i] = Bs + slot * 8;
    }

    f32x4 acc[4][4];
#pragma unroll
    for (int i = 0; i < 4; ++i)
#pragma unroll
        for (int j = 0; j < 4; ++j) acc[i][j] = f32x4{0.f, 0.f, 0.f, 0.f};

    for (int k0 = k_begin; k0 < k_end; k0 += 64) {
#pragma unroll
        for (int i = 0; i < 4; ++i) gload16(aDst[i], aSrc[i] + k0);
#pragma unroll
        for (int i = 0; i < 4; ++i) gload16(bDst[i], bSrc[i] + k0);
        asm volatile("s_waitcnt vmcnt(0)" ::: "memory");
        __syncthreads();
#pragma unroll
        for (int kk = 0; kk < 2; ++kk) {
            int kc = kk * 4 + kq;
            bf16x8 af[4], bfr[4];
#pragma unroll
            for (int i = 0; i < 4; ++i) {
                int rowA = wm * 64 + i * 16 + l15;
                af[i] = *(const bf16x8*)(As + rowA * 64 + kc * 8);
                int rowB = wn * 64 + i * 16 + l15;
                bfr[i] = *(const bf16x8*)(Bs + rowB * 64 + kc * 8);
            }
#pragma unroll
            for (int i = 0; i < 4; ++i)
#pragma unroll
                for (int j = 0; j < 4; ++j)
                    acc[i][j] = __builtin_amdgcn_mfma_f32_16x16x32_bf16(
                        af[i], bfr[j], acc[i][j], 0, 0, 0);
        }
        __syncthreads();
    }

    if constexpr (MODE == 0) {
        const float* b1e = b1 + (size_t)e * F_DIM;
#pragma unroll
        for (int i = 0; i < 4; ++i) {
            int gr = row0 + wm * 64 + i * 16 + kq * 4;
#pragma unroll
            for (int j = 0; j < 4; ++j) {
                int gc = n0 + wn * 64 + j * 16 + l15;
                float bb = b1e[gc];
#pragma unroll
                for (int r = 0; r < 4; ++r) {
                    float v = acc[i][j][r] + bb;
                    Hout[(size_t)(gr + r) * F_DIM + gc] = f2b(gelu_f(v));
                }
            }
        }
    } else {
        const float* b2e = b2 + (size_t)e * D_DIM;
        bool addBias = (k_begin == 0);
#pragma unroll
        for (int i = 0; i < 4; ++i) {
            int grb = row0 + wm * 64 + i * 16 + kq * 4;
#pragma unroll
            for (int r = 0; r < 4; ++r) {
                int tok = rowmap[grb + r];
                float g = rowgate[grb + r];
                if (tok >= 0 && tok < T_TOK) {
                    float* orow = outm + (size_t)tok * D_DIM;
#pragma unroll
                    for (int j = 0; j < 4; ++j) {
                        int gc = n0 + wn * 64 + j * 16 + l15;
                        float bb = addBias ? b2e[gc] : 0.f;
                        atomicAdd(orow + gc, g * (acc[i][j][r] + bb));
                    }
                }
            }
        }
    }
}

// ---------------- workspace layout (bytes) — total need ~81 MB --------------
#define OFF_AN      0u           // 16 KB fp32 a_n
#define OFF_CNT     0x10000u
#define OFF_OFFS    0x10100u
#define OFF_SYNC    0x10200u     // int[4]: routing_done counter
#define OFF_IDX     0x20000u     // int[T*2]
#define OFF_GATE    0x28000u     // float[T*2]
#define OFF_ROWMAP  0x30000u     // int[NROWS]
#define OFF_ROWGATE 0x40000u     // float[NROWS]
#define OFF_XG      0x900000u    // 9.44 MB u16[NROWS*D]  -> ends 0x1200000
#define OFF_W1T     0x1200000u   // 16.78 MB u16[E][F][D] -> ends 0x2200000
#define OFF_W2T     0x2200000u   // 16.78 MB u16[E][D][F] -> ends 0x3200000
#define OFF_HG      0x3200000u   // 37.75 MB u16[NROWS*F] -> ends 0x5600000

extern "C" void kernel_launch(void* const* d_in, const int* in_sizes, int n_in,
                              void* d_out, int out_size, void* d_ws, size_t ws_size,
                              hipStream_t stream) {
    const float* x       = (const float*)d_in[0];
    const float* anchors = (const float*)d_in[1];
    const float* W1      = (const float*)d_in[2];
    const float* b1      = (const float*)d_in[3];
    const float* W2      = (const float*)d_in[4];
    const float* b2      = (const float*)d_in[5];
    float* out = (float*)d_out;

    char* ws = (char*)d_ws;
    float* an      = (float*)(ws + OFF_AN);
    int*   cnt     = (int*)(ws + OFF_CNT);
    int*   offs    = (int*)(ws + OFF_OFFS);
    int*   syncw   = (int*)(ws + OFF_SYNC);
    int*   idxs    = (int*)(ws + OFF_IDX);
    float* gates   = (float*)(ws + OFF_GATE);
    int*   rowmap  = (int*)(ws + OFF_ROWMAP);
    float* rowgate = (float*)(ws + OFF_ROWGATE);
    u16*   Xg      = (u16*)(ws + OFF_XG);
    u16*   W1T     = (u16*)(ws + OFF_W1T);
    u16*   W2T     = (u16*)(ws + OFF_W2T);
    u16*   Hg      = (u16*)(ws + OFF_HG);

    // d_out sections (fp32 elements): out | a_n | scores | topk_idx
    float* out_main   = out;
    float* out_an     = out + (size_t)T_TOK * D_DIM;
    float* out_scores = out_an + E_EXP * D_DIM;
    float* out_idx    = out_scores + (size_t)T_TOK * E_EXP;

    init_k<<<512, 256, 0, stream>>>(cnt, rowmap, rowgate, out_main, syncw,
                                    anchors, an, out_an);
    route_trans_k<<<64 + 4096, 256, 0, stream>>>(
        x, an, out_scores, out_idx, idxs, gates, cnt, offs,
        rowmap, rowgate, W1, W1T, W2, W2T, syncw);
    gather_k<<<NROWS, 256, 0, stream>>>(x, rowmap, Xg);
    // gemm1: 16 n-tiles x 72 m-tiles = 1152 blocks (1D, XCD-swizzled)
    gemm_k<0><<<16 * MAXTILES, 256, 0, stream>>>(
        Xg, D_DIM, W1T, D_DIM, Hg, b1, nullptr, nullptr,
        rowmap, nullptr, offs, D_DIM, 16);
    // gemm2: 4 n-tiles x 72 m-tiles x splitK2 = 576 blocks (1D, XCD-swizzled)
    gemm_k<1><<<4 * MAXTILES * 2, 256, 0, stream>>>(
        Hg, F_DIM, W2T, F_DIM, nullptr, nullptr, out_main, b2,
        rowmap, rowgate, offs, F_DIM / 2, 4);
}